// Round 5
// baseline (565.412 us; speedup 1.0000x reference)
//
#include <hip/hip_runtime.h>

// ---------- types & helpers ----------
typedef __attribute__((ext_vector_type(8))) __bf16 bf16x8;
typedef __attribute__((ext_vector_type(4))) float f32x4;

#define DEVI __device__ __forceinline__

DEVI unsigned short f2bf(float f) {
    unsigned u = __builtin_bit_cast(unsigned, f);
    u += 0x7fffu + ((u >> 16) & 1u);
    return (unsigned short)(u >> 16);
}
DEVI float bf2f(unsigned short h) {
    unsigned u = ((unsigned)h) << 16;
    return __builtin_bit_cast(float, u);
}
DEVI float gelu_tanh(float x) {
    float u = 0.7978845608028654f * (x + 0.044715f * x * x * x);
    float t = 1.0f - 2.0f / (1.0f + __expf(2.0f * u));
    return 0.5f * x * (1.0f + t);
}
DEVI void gload16(const void* g, void* l) {
    __builtin_amdgcn_global_load_lds((const __attribute__((address_space(1))) unsigned int*)g,
                                     (__attribute__((address_space(3))) unsigned int*)l,
                                     16, 0, 0);
}

// problem constants
#define BB 8
#define SS 2048
#define DD 1024
#define EE 8
#define FF 2048
#define CC 320
#define NTOK (BB * SS)           // 16384
#define MPE (BB * CC)            // 2560 slots per expert
#define NSLOT (EE * MPE)         // 20480

// ---------- kernel 1: RMSNorm + gate + base output (data + mp*norm for ALL tokens) ----------
__global__ __launch_bounds__(256) void k_rms_gate(
    const float* __restrict__ data, const float* __restrict__ gate_w,
    const float* __restrict__ rms_w, unsigned short* __restrict__ norm_bf,
    float* __restrict__ logits_out, float* __restrict__ maxprob, int* __restrict__ eidx_out,
    float* __restrict__ outF)
{
    const int token = blockIdx.x;
    const int t = threadIdx.x;
    const float4 v = ((const float4*)(data + (size_t)token * DD))[t];
    float ss = v.x * v.x + v.y * v.y + v.z * v.z + v.w * v.w;
#pragma unroll
    for (int o = 32; o; o >>= 1) ss += __shfl_down(ss, o, 64);
    __shared__ float sred[4];
    __shared__ float slog[8];
    __shared__ float sacc[4][8];
    __shared__ float smp;
    if ((t & 63) == 0) sred[t >> 6] = ss;
    __syncthreads();
    const float tot = sred[0] + sred[1] + sred[2] + sred[3];
    const float scale = rsqrtf(tot * (1.0f / 1024.0f) + 1e-6f);
    const float4 w = ((const float4*)rms_w)[t];
    float nn[4] = { v.x * scale * w.x, v.y * scale * w.y, v.z * scale * w.z, v.w * scale * w.w };
    ushort4 nb;
    nb.x = f2bf(nn[0]); nb.y = f2bf(nn[1]); nb.z = f2bf(nn[2]); nb.w = f2bf(nn[3]);
    ((ushort4*)(norm_bf + (size_t)token * DD))[t] = nb;

    float acc[8] = {0, 0, 0, 0, 0, 0, 0, 0};
    const float4* g = (const float4*)(gate_w + t * 32);
#pragma unroll
    for (int d = 0; d < 4; ++d) {
        float4 p = g[2 * d], q = g[2 * d + 1];
        acc[0] += nn[d] * p.x; acc[1] += nn[d] * p.y; acc[2] += nn[d] * p.z; acc[3] += nn[d] * p.w;
        acc[4] += nn[d] * q.x; acc[5] += nn[d] * q.y; acc[6] += nn[d] * q.z; acc[7] += nn[d] * q.w;
    }
#pragma unroll
    for (int e = 0; e < 8; ++e) {
#pragma unroll
        for (int o = 32; o; o >>= 1) acc[e] += __shfl_down(acc[e], o, 64);
    }
    if ((t & 63) == 0) {
#pragma unroll
        for (int e = 0; e < 8; ++e) sacc[t >> 6][e] = acc[e];
    }
    __syncthreads();
    if (t < 8) {
        float l = sacc[0][t] + sacc[1][t] + sacc[2][t] + sacc[3][t];
        logits_out[(size_t)token * 8 + t] = l;
        slog[t] = l;
    }
    __syncthreads();
    if (t == 0) {
        float m = slog[0]; int am = 0;
#pragma unroll
        for (int e = 1; e < 8; ++e) { if (slog[e] > m) { m = slog[e]; am = e; } }
        float s = 0.f;
#pragma unroll
        for (int e = 0; e < 8; ++e) s += __expf(slog[e] - m);
        const float mp = 1.0f / s;
        maxprob[token] = mp;
        smp = mp;
        eidx_out[token] = am;
    }
    __syncthreads();
    const float mp = smp;
    float4 o;
    o.x = v.x + mp * nn[0]; o.y = v.y + mp * nn[1];
    o.z = v.z + mp * nn[2]; o.w = v.w + mp * nn[3];
    ((float4*)(outF + (size_t)token * DD))[t] = o;   // base; GEMM2 overwrites kept rows
}

// ---------- kernel 2: routing scan (per batch) + zero-page init ----------
__global__ __launch_bounds__(256) void k_route(
    const int* __restrict__ eidx, float* __restrict__ idxf_out,
    int* __restrict__ slot_token, int* __restrict__ zp)
{
    const int b = blockIdx.x, t = threadIdx.x;
    if (b == 0) { zp[t] = 0; zp[t + 256] = 0; zp[t + 512] = 0; zp[t + 768] = 0; }
    for (int i = t; i < EE * CC; i += 256) {
        int e = i / CC, c = i % CC;
        slot_token[e * MPE + b * CC + c] = -1;
    }
    const int base = b * SS + t * 8;
    int e8[8];
#pragma unroll
    for (int j = 0; j < 8; ++j) e8[j] = eidx[base + j];
    int cnt[8] = {0, 0, 0, 0, 0, 0, 0, 0};
#pragma unroll
    for (int j = 0; j < 8; ++j) {
#pragma unroll
        for (int q = 0; q < 8; ++q) cnt[q] += (e8[j] == q);
    }
    __shared__ int sc[8][256];
#pragma unroll
    for (int q = 0; q < 8; ++q) sc[q][t] = cnt[q];
    __syncthreads();
    for (int off = 1; off < 256; off <<= 1) {
        int v[8];
#pragma unroll
        for (int q = 0; q < 8; ++q) v[q] = (t >= off) ? sc[q][t - off] : 0;
        __syncthreads();
#pragma unroll
        for (int q = 0; q < 8; ++q) sc[q][t] += v[q];
        __syncthreads();
    }
    int run[8];
#pragma unroll
    for (int q = 0; q < 8; ++q) run[q] = (t == 0) ? 0 : sc[q][t - 1];
#pragma unroll
    for (int j = 0; j < 8; ++j) {
        const int e = e8[j];
        const int tok = base + j;
        int pos = 0;
#pragma unroll
        for (int q = 0; q < 8; ++q) if (q == e) { pos = run[q]; run[q]++; }
        const bool kept = pos < CC;
        idxf_out[tok] = (float)(kept ? e : 0);
        if (kept) slot_token[e * MPE + b * CC + pos] = tok;
    }
}

// ---------- kernel 3: transpose+convert both weights, 64x64 tiles ----------
__global__ __launch_bounds__(256) void k_transcvt3(
    const float* __restrict__ w1, const float* __restrict__ w2,
    unsigned short* __restrict__ w1T, unsigned short* __restrict__ w2T)
{
    __shared__ float tile[64][68];
    const int bid = blockIdx.x, t = threadIdx.x;
    const float* src; unsigned short* dst; int C, R, tr, tc;
    if (bid < 4096) {
        const int e = bid >> 9, rem = bid & 511;
        tr = rem >> 5; tc = rem & 31;               // 16 x 32 tiles
        src = w1 + (size_t)e * (DD * FF); dst = w1T + (size_t)e * (DD * FF);
        R = DD; C = FF;
    } else {
        const int b2 = bid - 4096;
        const int e = b2 >> 9, rem = b2 & 511;
        tr = rem >> 4; tc = rem & 15;               // 32 x 16 tiles
        src = w2 + (size_t)e * (DD * FF); dst = w2T + (size_t)e * (DD * FF);
        R = FF; C = DD;
    }
    const int r = t >> 2, c0 = (t & 3) << 4;
    const float4* sp = (const float4*)(src + (size_t)(tr * 64 + r) * C + tc * 64 + c0);
#pragma unroll
    for (int i = 0; i < 4; ++i) *(float4*)&tile[r][c0 + 4 * i] = sp[i];
    __syncthreads();
    const int oc = t >> 2, i0 = (t & 3) << 4;
    union { unsigned short us[16]; int4 q[2]; } u;
#pragma unroll
    for (int i = 0; i < 16; ++i) u.us[i] = f2bf(tile[i0 + i][oc]);
    unsigned short* dp = dst + (size_t)(tc * 64 + oc) * R + tr * 64 + i0;
    *(int4*)dp = u.q[0];
    *(int4*)(dp + 8) = u.q[1];
}

// ---------- 256x256 8-phase GEMM (T2+T3+T4+T5), BK=64, 512 threads ----------
// C[M][N] = A[M][K] * Bt[N][K]^T per expert. MODE 0: A gathered, epi gelu->H.
// MODE 1: A dense (Hbuf), epi scatter outF = data + mp*y.
// LDS per buf(2): A halves [h][wm][64r][128B], B halves [h][wn][32r][128B]; st_16x32 swizzle.
#define LD_A(buf, h) { _Pragma("unroll") for (int mp_ = 0; mp_ < 4; ++mp_) { \
    const int lr_ = mp_ * 16 + rr; \
    _Pragma("unroll") for (int ks_ = 0; ks_ < 2; ++ks_) \
      ar_[mp_][ks_] = *(const bf16x8*)(sm + (buf) * 65536 + (h) * 16384 + wm * 8192 + lr_ * 128 + ((ks_ * 64 + g * 16) ^ (((lr_ >> 2) & 1) << 5))); } }

#define LD_B(buf, h, reg) { _Pragma("unroll") for (int np_ = 0; np_ < 2; ++np_) { \
    const int lr_ = np_ * 16 + rr; \
    _Pragma("unroll") for (int ks_ = 0; ks_ < 2; ++ks_) \
      reg[np_][ks_] = *(const bf16x8*)(sm + (buf) * 65536 + 32768 + (h) * 16384 + wn * 4096 + lr_ * 128 + ((ks_ * 64 + g * 16) ^ (((lr_ >> 2) & 1) << 5))); } }

#define MM(qa, qb, reg) { _Pragma("unroll") for (int ks_ = 0; ks_ < 2; ++ks_) \
    _Pragma("unroll") for (int mp_ = 0; mp_ < 4; ++mp_) \
    _Pragma("unroll") for (int np_ = 0; np_ < 2; ++np_) \
      acc[(qa) * 4 + mp_][(qb) * 2 + np_] = __builtin_amdgcn_mfma_f32_16x16x32_bf16(ar_[mp_][ks_], reg[np_][ks_], acc[(qa) * 4 + mp_][(qb) * 2 + np_], 0, 0, 0); }

#define ST_A(buf, h, kt) { \
    gload16(srcA[h][0] + (kt) * 64, sm + (buf) * 65536 + (h) * 16384 + tid * 16); \
    gload16(srcA[h][1] + (kt) * 64, sm + (buf) * 65536 + (h) * 16384 + 8192 + tid * 16); }
#define ST_B(buf, h, kt) { \
    gload16(srcB[h][0] + (kt) * 64, sm + (buf) * 65536 + 32768 + (h) * 16384 + tid * 16); \
    gload16(srcB[h][1] + (kt) * 64, sm + (buf) * 65536 + 32768 + (h) * 16384 + 8192 + tid * 16); }

#define PH_TOP  __builtin_amdgcn_s_barrier(); \
                asm volatile("s_waitcnt lgkmcnt(0)" ::: "memory"); \
                __builtin_amdgcn_s_setprio(1)
#define PH_END  __builtin_amdgcn_s_setprio(0); __builtin_amdgcn_s_barrier()
#define PH_END_VM4 __builtin_amdgcn_s_setprio(0); \
                asm volatile("s_waitcnt vmcnt(4)" ::: "memory"); __builtin_amdgcn_s_barrier()
#define PH_END_VM0 __builtin_amdgcn_s_setprio(0); \
                asm volatile("s_waitcnt vmcnt(0)" ::: "memory"); __builtin_amdgcn_s_barrier()

template <int MODE, int K, int NT_N>
__global__ __launch_bounds__(512) void k_gemm8(
    const unsigned short* __restrict__ Ap, const unsigned short* __restrict__ Bt,
    unsigned short* __restrict__ H, const int* __restrict__ slot_token,
    const float* __restrict__ maxprob, const float* __restrict__ data,
    float* __restrict__ outF, const unsigned short* __restrict__ zp)
{
    __shared__ __align__(16) unsigned char sm[131072];
    const int bid = blockIdx.x;
    const int e = bid & 7;                  // expert == XCD (grid % 8 == 0, bijective)
    const int inner = bid >> 3;
    const int tm = inner / NT_N, tn = inner % NT_N;
    const int tid = threadIdx.x;
    const int L = tid & 63;
    const int wm = tid >> 8;                // 2 M-halves of waves
    const int wn = (tid >> 6) & 3;          // 4 N-quarters
    const int rr = L & 15, g = L >> 4;
    const int slot0 = e * MPE + tm * 256;
    const int N = NT_N * 256;

    // pre-swizzled per-lane stage source pointers (inverse-swz source, linear LDS dest)
    const unsigned short* srcA[2][2];
    const unsigned short* srcB[2][2];
#pragma unroll
    for (int h = 0; h < 2; ++h)
#pragma unroll
      for (int p = 0; p < 2; ++p) {
        const int o = p * 8192 + tid * 16;
        const int lo = o ^ (((o >> 9) & 1) << 5);
        const int cb = lo & 127;
        const int arr = (lo >> 7) & 63;
        const int arow = p * 128 + h * 64 + arr;
        if (MODE == 0) {
            const int tok = slot_token[slot0 + arow];
            srcA[h][p] = (tok < 0 ? zp : Ap + (size_t)tok * (size_t)K) + (cb >> 1);
        } else {
            srcA[h][p] = Ap + (size_t)(slot0 + arow) * (size_t)K + (cb >> 1);
        }
        const int bwn = o >> 12;
        const int brr = (lo >> 7) & 31;
        const int nrow = tn * 256 + bwn * 64 + h * 32 + brr;
        srcB[h][p] = Bt + ((size_t)e * N + nrow) * (size_t)K + (cb >> 1);
    }

    f32x4 acc[8][4];
#pragma unroll
    for (int m = 0; m < 8; ++m)
#pragma unroll
      for (int n = 0; n < 4; ++n) acc[m][n] = 0.f;
    bf16x8 ar_[4][2], br0_[2][2], br1_[2][2];

    // prologue: tile0 all units + tile1 A0,B1  (12 loads); drain to 4
    ST_A(0, 0, 0); ST_B(0, 0, 0); ST_A(0, 1, 0); ST_B(0, 1, 0);
    ST_A(1, 0, 1); ST_B(1, 1, 1);
    asm volatile("s_waitcnt vmcnt(4)" ::: "memory");
    __builtin_amdgcn_s_barrier();

    const int NT = K / 64;
    const int NITER = NT / 2;
    for (int it = 0; it < NITER - 1; ++it) {
        const int t1 = 2 * it + 1;
        // ph1: Q(0,0) of t0 (buf0); stage A1(t1)->buf1
        LD_A(0, 0); LD_B(0, 0, br0_); ST_A(1, 1, t1);
        PH_TOP; MM(0, 0, br0_); PH_END;
        // ph2: Q(0,1); stage B0(t1)
        LD_B(0, 1, br1_); ST_B(1, 0, t1);
        PH_TOP; MM(0, 1, br1_); PH_END;
        // ph3: Q(1,1); stage A0(t0+2)->buf0
        LD_A(0, 1); ST_A(0, 0, t1 + 1);
        PH_TOP; MM(1, 1, br1_); PH_END;
        // ph4: Q(1,0); stage B1(t0+2); counted wait covers tile t1
        ST_B(0, 1, t1 + 1);
        PH_TOP; MM(1, 0, br0_); PH_END_VM4;
        // ph5: Q(0,0) of t1 (buf1); stage A1(t0+2)
        LD_A(1, 0); LD_B(1, 0, br0_); ST_A(0, 1, t1 + 1);
        PH_TOP; MM(0, 0, br0_); PH_END;
        // ph6: Q(0,1); stage B0(t0+2)
        LD_B(1, 1, br1_); ST_B(0, 0, t1 + 1);
        PH_TOP; MM(0, 1, br1_); PH_END;
        // ph7: Q(1,1); stage A0(t1+2)->buf1
        LD_A(1, 1); ST_A(1, 0, t1 + 2);
        PH_TOP; MM(1, 1, br1_); PH_END;
        // ph8: Q(1,0); stage B1(t1+2); counted wait covers tile t0+2
        ST_B(1, 1, t1 + 2);
        PH_TOP; MM(1, 0, br0_); PH_END_VM4;
    }
    {   // last iteration: tiles NT-2, NT-1; only t1 stages remain
        LD_A(0, 0); LD_B(0, 0, br0_); ST_A(1, 1, NT - 1);
        PH_TOP; MM(0, 0, br0_); PH_END;
        LD_B(0, 1, br1_); ST_B(1, 0, NT - 1);
        PH_TOP; MM(0, 1, br1_); PH_END;
        LD_A(0, 1);
        PH_TOP; MM(1, 1, br1_); PH_END;
        PH_TOP; MM(1, 0, br0_); PH_END_VM0;
        LD_A(1, 0); LD_B(1, 0, br0_);
        PH_TOP; MM(0, 0, br0_); PH_END;
        LD_B(1, 1, br1_);
        PH_TOP; MM(0, 1, br1_); PH_END;
        LD_A(1, 1);
        PH_TOP; MM(1, 1, br1_); PH_END;
        PH_TOP; MM(1, 0, br0_); PH_END;
    }

    // epilogue: re-layout via LDS [128][260] in two M-halves, then coalesced out
    unsigned short* lo16 = (unsigned short*)sm;
#pragma unroll
    for (int hb = 0; hb < 2; ++hb) {
        if (wm == hb) {
#pragma unroll
            for (int m = 0; m < 8; ++m)
#pragma unroll
              for (int n = 0; n < 4; ++n) {
                f32x4 a = acc[m][n];
#pragma unroll
                for (int j = 0; j < 4; ++j) {
                    float x = a[j];
                    if (MODE == 0) x = gelu_tanh(x);
                    lo16[(m * 16 + g * 4 + j) * 260 + wn * 64 + n * 16 + rr] = f2bf(x);
                }
              }
        }
        __syncthreads();
#pragma unroll
        for (int rd = 0; rd < 8; ++rd) {
            const int idx = rd * 512 + tid;
            const int row = idx >> 5, c8 = (idx & 31) << 3;
            if (MODE == 0) {
                int4 v = *(const int4*)(lo16 + row * 260 + c8);
                *(int4*)(H + (size_t)(slot0 + hb * 128 + row) * FF + (size_t)tn * 256 + c8) = v;
            } else {
                const int tok = slot_token[slot0 + hb * 128 + row];
                if (tok >= 0) {
                    const float mp = maxprob[tok];
                    int4 yv = *(const int4*)(lo16 + row * 260 + c8);
                    const unsigned short* yy = (const unsigned short*)&yv;
                    const size_t go = (size_t)tok * DD + (size_t)tn * 256 + c8;
                    float4 d0 = *(const float4*)(data + go);
                    float4 d1 = *(const float4*)(data + go + 4);
                    float4 o0, o1;
                    o0.x = d0.x + mp * bf2f(yy[0]); o0.y = d0.y + mp * bf2f(yy[1]);
                    o0.z = d0.z + mp * bf2f(yy[2]); o0.w = d0.w + mp * bf2f(yy[3]);
                    o1.x = d1.x + mp * bf2f(yy[4]); o1.y = d1.y + mp * bf2f(yy[5]);
                    o1.z = d1.z + mp * bf2f(yy[6]); o1.w = d1.w + mp * bf2f(yy[7]);
                    *(float4*)(outF + go) = o0;
                    *(float4*)(outF + go + 4) = o1;
                }
            }
        }
        __syncthreads();
    }
}

// ---------- launch ----------
extern "C" void kernel_launch(void* const* d_in, const int* in_sizes, int n_in,
                              void* d_out, int out_size, void* d_ws, size_t ws_size,
                              hipStream_t stream)
{
    (void)in_sizes; (void)n_in; (void)out_size; (void)ws_size;
    const float* data   = (const float*)d_in[0];
    const float* gate_w = (const float*)d_in[1];
    const float* w1     = (const float*)d_in[2];
    const float* w2     = (const float*)d_in[3];
    const float* rms_w  = (const float*)d_in[4];

    float* outF   = (float*)d_out;
    float* logits = outF + (size_t)NTOK * DD;
    float* idxf   = logits + (size_t)NTOK * EE;

    char* ws = (char*)d_ws;
    const size_t SZ_NORM = (size_t)NTOK * DD * 2;        // 32 MB
    const size_t SZ_W1T  = (size_t)EE * DD * FF * 2;     // 32 MB
    const size_t SZ_W2T  = SZ_W1T;                       // 32 MB
    const size_t SZ_H    = (size_t)NSLOT * FF * 2;       // 80 MB
    unsigned short* norm_bf = (unsigned short*)(ws);
    unsigned short* w1T     = (unsigned short*)(ws + SZ_NORM);
    unsigned short* w2T     = (unsigned short*)(ws + SZ_NORM + SZ_W1T);
    unsigned short* Hbuf    = (unsigned short*)(ws + SZ_NORM + SZ_W1T + SZ_W2T);
    char* small             = ws + SZ_NORM + SZ_W1T + SZ_W2T + SZ_H;
    int*   slot_token = (int*)(small);
    int*   eidx       = (int*)(small + NSLOT * 4);
    float* maxprob    = (float*)(small + NSLOT * 4 + NTOK * 4);
    int*   zp         = (int*)(small + NSLOT * 4 + NTOK * 4 + NTOK * 4);

    k_rms_gate<<<NTOK, 256, 0, stream>>>(data, gate_w, rms_w, norm_bf, logits, maxprob, eidx, outF);
    k_route<<<BB, 256, 0, stream>>>(eidx, idxf, slot_token, zp);
    k_transcvt3<<<8192, 256, 0, stream>>>(w1, w2, w1T, w2T);
    k_gemm8<0, 1024, 8><<<640, 512, 0, stream>>>(norm_bf, w1T, Hbuf, slot_token,
                                                 nullptr, nullptr, nullptr, (const unsigned short*)zp);
    k_gemm8<1, 2048, 4><<<320, 512, 0, stream>>>(Hbuf, w2T, nullptr, slot_token,
                                                 maxprob, data, outF, nullptr);
}

// Round 7
// 531.346 us; speedup vs baseline: 1.0641x; 1.0641x over previous
//
#include <hip/hip_runtime.h>

// ---------- types & helpers ----------
typedef __attribute__((ext_vector_type(8))) __bf16 bf16x8;
typedef __attribute__((ext_vector_type(4))) float f32x4;

#define DEVI __device__ __forceinline__

DEVI unsigned short f2bf(float f) {
    unsigned u = __builtin_bit_cast(unsigned, f);
    u += 0x7fffu + ((u >> 16) & 1u);
    return (unsigned short)(u >> 16);
}
DEVI float bf2f(unsigned short h) {
    unsigned u = ((unsigned)h) << 16;
    return __builtin_bit_cast(float, u);
}
DEVI float gelu_tanh(float x) {
    float u = 0.7978845608028654f * (x + 0.044715f * x * x * x);
    float t = 1.0f - 2.0f / (1.0f + __expf(2.0f * u));
    return 0.5f * x * (1.0f + t);
}
DEVI void gload16(const void* g, void* l) {
    __builtin_amdgcn_global_load_lds((const __attribute__((address_space(1))) unsigned int*)g,
                                     (__attribute__((address_space(3))) unsigned int*)l,
                                     16, 0, 0);
}

// problem constants
#define BB 8
#define SS 2048
#define DD 1024
#define EE 8
#define FF 2048
#define CC 320
#define NTOK (BB * SS)           // 16384
#define MPE (BB * CC)            // 2560 slots per expert
#define NSLOT (EE * MPE)         // 20480

// ---------- kernel 1: RMSNorm + gate + base output (data + mp*norm for ALL tokens) ----------
__global__ __launch_bounds__(256) void k_rms_gate(
    const float* __restrict__ data, const float* __restrict__ gate_w,
    const float* __restrict__ rms_w, unsigned short* __restrict__ norm_bf,
    float* __restrict__ logits_out, float* __restrict__ maxprob, int* __restrict__ eidx_out,
    float* __restrict__ outF)
{
    const int token = blockIdx.x;
    const int t = threadIdx.x;
    const float4 v = ((const float4*)(data + (size_t)token * DD))[t];
    float ss = v.x * v.x + v.y * v.y + v.z * v.z + v.w * v.w;
#pragma unroll
    for (int o = 32; o; o >>= 1) ss += __shfl_down(ss, o, 64);
    __shared__ float sred[4];
    __shared__ float slog[8];
    __shared__ float sacc[4][8];
    __shared__ float smp;
    if ((t & 63) == 0) sred[t >> 6] = ss;
    __syncthreads();
    const float tot = sred[0] + sred[1] + sred[2] + sred[3];
    const float scale = rsqrtf(tot * (1.0f / 1024.0f) + 1e-6f);
    const float4 w = ((const float4*)rms_w)[t];
    float nn[4] = { v.x * scale * w.x, v.y * scale * w.y, v.z * scale * w.z, v.w * scale * w.w };
    ushort4 nb;
    nb.x = f2bf(nn[0]); nb.y = f2bf(nn[1]); nb.z = f2bf(nn[2]); nb.w = f2bf(nn[3]);
    ((ushort4*)(norm_bf + (size_t)token * DD))[t] = nb;

    float acc[8] = {0, 0, 0, 0, 0, 0, 0, 0};
    const float4* g = (const float4*)(gate_w + t * 32);
#pragma unroll
    for (int d = 0; d < 4; ++d) {
        float4 p = g[2 * d], q = g[2 * d + 1];
        acc[0] += nn[d] * p.x; acc[1] += nn[d] * p.y; acc[2] += nn[d] * p.z; acc[3] += nn[d] * p.w;
        acc[4] += nn[d] * q.x; acc[5] += nn[d] * q.y; acc[6] += nn[d] * q.z; acc[7] += nn[d] * q.w;
    }
#pragma unroll
    for (int e = 0; e < 8; ++e) {
#pragma unroll
        for (int o = 32; o; o >>= 1) acc[e] += __shfl_down(acc[e], o, 64);
    }
    if ((t & 63) == 0) {
#pragma unroll
        for (int e = 0; e < 8; ++e) sacc[t >> 6][e] = acc[e];
    }
    __syncthreads();
    if (t < 8) {
        float l = sacc[0][t] + sacc[1][t] + sacc[2][t] + sacc[3][t];
        logits_out[(size_t)token * 8 + t] = l;
        slog[t] = l;
    }
    __syncthreads();
    if (t == 0) {
        float m = slog[0]; int am = 0;
#pragma unroll
        for (int e = 1; e < 8; ++e) { if (slog[e] > m) { m = slog[e]; am = e; } }
        float s = 0.f;
#pragma unroll
        for (int e = 0; e < 8; ++e) s += __expf(slog[e] - m);
        const float mp = 1.0f / s;
        maxprob[token] = mp;
        smp = mp;
        eidx_out[token] = am;
    }
    __syncthreads();
    const float mp = smp;
    float4 o;
    o.x = v.x + mp * nn[0]; o.y = v.y + mp * nn[1];
    o.z = v.z + mp * nn[2]; o.w = v.w + mp * nn[3];
    ((float4*)(outF + (size_t)token * DD))[t] = o;   // base; GEMM2 overwrites kept rows
}

// ---------- kernel 2: routing scan (per batch) + zero-page init ----------
__global__ __launch_bounds__(256) void k_route(
    const int* __restrict__ eidx, float* __restrict__ idxf_out,
    int* __restrict__ slot_token, int* __restrict__ zp)
{
    const int b = blockIdx.x, t = threadIdx.x;
    if (b == 0) { zp[t] = 0; zp[t + 256] = 0; zp[t + 512] = 0; zp[t + 768] = 0; }
    for (int i = t; i < EE * CC; i += 256) {
        int e = i / CC, c = i % CC;
        slot_token[e * MPE + b * CC + c] = -1;
    }
    const int base = b * SS + t * 8;
    int e8[8];
#pragma unroll
    for (int j = 0; j < 8; ++j) e8[j] = eidx[base + j];
    int cnt[8] = {0, 0, 0, 0, 0, 0, 0, 0};
#pragma unroll
    for (int j = 0; j < 8; ++j) {
#pragma unroll
        for (int q = 0; q < 8; ++q) cnt[q] += (e8[j] == q);
    }
    __shared__ int sc[8][256];
#pragma unroll
    for (int q = 0; q < 8; ++q) sc[q][t] = cnt[q];
    __syncthreads();
    for (int off = 1; off < 256; off <<= 1) {
        int v[8];
#pragma unroll
        for (int q = 0; q < 8; ++q) v[q] = (t >= off) ? sc[q][t - off] : 0;
        __syncthreads();
#pragma unroll
        for (int q = 0; q < 8; ++q) sc[q][t] += v[q];
        __syncthreads();
    }
    int run[8];
#pragma unroll
    for (int q = 0; q < 8; ++q) run[q] = (t == 0) ? 0 : sc[q][t - 1];
#pragma unroll
    for (int j = 0; j < 8; ++j) {
        const int e = e8[j];
        const int tok = base + j;
        int pos = 0;
#pragma unroll
        for (int q = 0; q < 8; ++q) if (q == e) { pos = run[q]; run[q]++; }
        const bool kept = pos < CC;
        idxf_out[tok] = (float)(kept ? e : 0);
        if (kept) slot_token[e * MPE + b * CC + pos] = tok;
    }
}

// ---------- kernel 3: transpose+convert both weights, 64x64 tiles ----------
__global__ __launch_bounds__(256) void k_transcvt3(
    const float* __restrict__ w1, const float* __restrict__ w2,
    unsigned short* __restrict__ w1T, unsigned short* __restrict__ w2T)
{
    __shared__ float tile[64][68];
    const int bid = blockIdx.x, t = threadIdx.x;
    const float* src; unsigned short* dst; int C, R, tr, tc;
    if (bid < 4096) {
        const int e = bid >> 9, rem = bid & 511;
        tr = rem >> 5; tc = rem & 31;               // 16 x 32 tiles
        src = w1 + (size_t)e * (DD * FF); dst = w1T + (size_t)e * (DD * FF);
        R = DD; C = FF;
    } else {
        const int b2 = bid - 4096;
        const int e = b2 >> 9, rem = b2 & 511;
        tr = rem >> 4; tc = rem & 15;               // 32 x 16 tiles
        src = w2 + (size_t)e * (DD * FF); dst = w2T + (size_t)e * (DD * FF);
        R = FF; C = DD;
    }
    const int r = t >> 2, c0 = (t & 3) << 4;
    const float4* sp = (const float4*)(src + (size_t)(tr * 64 + r) * C + tc * 64 + c0);
#pragma unroll
    for (int i = 0; i < 4; ++i) *(float4*)&tile[r][c0 + 4 * i] = sp[i];
    __syncthreads();
    const int oc = t >> 2, i0 = (t & 3) << 4;
    union { unsigned short us[16]; int4 q[2]; } u;
#pragma unroll
    for (int i = 0; i < 16; ++i) u.us[i] = f2bf(tile[i0 + i][oc]);
    unsigned short* dp = dst + (size_t)(tc * 64 + oc) * R + tr * 64 + i0;
    *(int4*)dp = u.q[0];
    *(int4*)(dp + 8) = u.q[1];
}

// ---------- 256x128 4-phase GEMM (T2 full-row swizzle + T3/T4 counted vmcnt + T5) ----------
// 512 thr, 8 waves (2M x 4N), wave = 128 rows x 32 cols, 16 MFMA/phase, BK=64.
// LDS 96KB: A[buf][h]{16KB: [wm][64r][128B]} + B[buf][bh]{8KB: [wn][16r][128B]}.
// Swizzle: LDS[row][c] holds source col (c ^ ((row&7)<<4)); reads XOR same key.
#define AOFF(buf, h) ((buf) * 32768 + (h) * 16384)
#define BOFF(buf, bh) (65536 + (buf) * 16384 + (bh) * 8192)

#define ST_A(buf, h, kt) { \
    gload16(srcA[h][0] + (kt) * 64, sm + AOFF(buf, h) + tid * 16); \
    gload16(srcA[h][1] + (kt) * 64, sm + AOFF(buf, h) + 8192 + tid * 16); }
#define ST_B(buf, bh, kt) { \
    gload16(srcB[bh] + (kt) * 64, sm + BOFF(buf, bh) + tid * 16); }

#define LD_A(buf, h) { _Pragma("unroll") for (int mp_ = 0; mp_ < 4; ++mp_) { \
    _Pragma("unroll") for (int ks_ = 0; ks_ < 2; ++ks_) \
      ar_[mp_][ks_] = *(const bf16x8*)(sm + AOFF(buf, h) + wm * 8192 + (mp_ * 16 + rr) * 128 \
                                       + ((ks_ * 64 + g * 16) ^ ((rr & 7) << 4))); } }
#define LD_B(buf) { _Pragma("unroll") for (int qb_ = 0; qb_ < 2; ++qb_) { \
    _Pragma("unroll") for (int ks_ = 0; ks_ < 2; ++ks_) \
      br_[qb_][ks_] = *(const bf16x8*)(sm + BOFF(buf, qb_) + wn * 2048 + rr * 128 \
                                       + ((ks_ * 64 + g * 16) ^ ((rr & 7) << 4))); } }

#define MM(qa) { _Pragma("unroll") for (int ks_ = 0; ks_ < 2; ++ks_) \
    _Pragma("unroll") for (int mp_ = 0; mp_ < 4; ++mp_) \
    _Pragma("unroll") for (int qb_ = 0; qb_ < 2; ++qb_) \
      acc[(qa) * 4 + mp_][qb_] = __builtin_amdgcn_mfma_f32_16x16x32_bf16(ar_[mp_][ks_], br_[qb_][ks_], acc[(qa) * 4 + mp_][qb_], 0, 0, 0); }

#define PH_TOP  __builtin_amdgcn_s_barrier(); \
                asm volatile("s_waitcnt lgkmcnt(0)" ::: "memory"); \
                __builtin_amdgcn_s_setprio(1)
#define PH_END  __builtin_amdgcn_s_setprio(0); __builtin_amdgcn_s_barrier()
#define PH_END_VM3 __builtin_amdgcn_s_setprio(0); \
                asm volatile("s_waitcnt vmcnt(3)" ::: "memory"); __builtin_amdgcn_s_barrier()
#define PH_END_VM0 __builtin_amdgcn_s_setprio(0); \
                asm volatile("s_waitcnt vmcnt(0)" ::: "memory"); __builtin_amdgcn_s_barrier()

template <int MODE, int K, int NN>
__global__ __launch_bounds__(512) void k_gemm4(
    const unsigned short* __restrict__ Ap, const unsigned short* __restrict__ Bt,
    unsigned short* __restrict__ H, const int* __restrict__ slot_token,
    const float* __restrict__ maxprob, const float* __restrict__ data,
    float* __restrict__ outF, const unsigned short* __restrict__ zp)
{
    __shared__ __align__(16) unsigned char sm[98304];
    const int ntn = NN >> 7;
    const int bid = blockIdx.x;
    const int e = bid & 7;                  // expert == XCD (grid % 8 == 0)
    const int inner = bid >> 3;
    const int tm = inner / ntn, tn = inner % ntn;
    const int tid = threadIdx.x;
    const int L = tid & 63;
    const int wm = tid >> 8;                // 2 M-halves
    const int wn = (tid >> 6) & 3;          // 4 N-quarters (32 cols each)
    const int rr = L & 15, g = L >> 4;
    const int slot0 = e * MPE + tm * 256;

    // pre-swizzled per-lane stage source pointers (inverse swizzle on SOURCE, linear LDS dest)
    const unsigned short* srcA[2][2];
    const unsigned short* srcB[2];
#pragma unroll
    for (int h = 0; h < 2; ++h)
#pragma unroll
      for (int p = 0; p < 2; ++p) {
        const int o = p * 8192 + tid * 16;
        const int cb = (o & 127) ^ (((o >> 7) & 7) << 4);
        const int arow = p * 128 + h * 64 + ((o >> 7) & 63);
        if (MODE == 0) {
            const int tok = slot_token[slot0 + arow];
            srcA[h][p] = (tok < 0 ? zp : Ap + (size_t)tok * (size_t)K) + (cb >> 1);
        } else {
            srcA[h][p] = Ap + (size_t)(slot0 + arow) * (size_t)K + (cb >> 1);
        }
      }
#pragma unroll
    for (int bh = 0; bh < 2; ++bh) {
        const int o = tid * 16;
        const int cb = (o & 127) ^ (((o >> 7) & 7) << 4);
        const int nrow = tn * 128 + (o >> 11) * 32 + bh * 16 + ((o >> 7) & 15);
        srcB[bh] = Bt + ((size_t)e * NN + nrow) * (size_t)K + (cb >> 1);
    }

    f32x4 acc[8][2];
#pragma unroll
    for (int m = 0; m < 8; ++m) { acc[m][0] = 0.f; acc[m][1] = 0.f; }
    bf16x8 ar_[4][2], br_[2][2];

    // prologue: t0 fully (6 loads) + t1's A0,B1 (3); drain oldest 6
    ST_A(0, 0, 0); ST_B(0, 1, 0); ST_A(0, 1, 0); ST_B(0, 0, 0);
    ST_A(1, 0, 1); ST_B(1, 1, 1);
    asm volatile("s_waitcnt vmcnt(3)" ::: "memory");
    __builtin_amdgcn_s_barrier();

    const int NT = K / 64;
    for (int it = 0; it < NT / 2 - 1; ++it) {
        const int v = 2 * it + 1;
        // P1: u-h0 (buf0); stage A1(v),B0(v) -> buf1
        LD_A(0, 0); LD_B(0); ST_A(1, 1, v); ST_B(1, 0, v);
        PH_TOP; MM(0); PH_END;
        // P2: u-h1; stage A0(u+2),B1(u+2) -> buf0; counted wait completes tile v
        LD_A(0, 1); ST_A(0, 0, v + 1); ST_B(0, 1, v + 1);
        PH_TOP; MM(1); PH_END_VM3;
        // P3: v-h0 (buf1); stage A1(u+2),B0(u+2) -> buf0
        LD_A(1, 0); LD_B(1); ST_A(0, 1, v + 1); ST_B(0, 0, v + 1);
        PH_TOP; MM(0); PH_END;
        // P4: v-h1; stage A0(v+2),B1(v+2) -> buf1; counted wait completes tile u+2
        LD_A(1, 1); ST_A(1, 0, v + 2); ST_B(1, 1, v + 2);
        PH_TOP; MM(1); PH_END_VM3;
    }
    {   // last iteration: tiles NT-2 (buf0), NT-1 (buf1)
        LD_A(0, 0); LD_B(0); ST_A(1, 1, NT - 1); ST_B(1, 0, NT - 1);
        PH_TOP; MM(0); PH_END;
        LD_A(0, 1);
        PH_TOP; MM(1); PH_END_VM0;
        LD_A(1, 0); LD_B(1);
        PH_TOP; MM(0); PH_END;
        LD_A(1, 1);
        PH_TOP; MM(1); PH_END;
    }

    // epilogue: per M-half, stage 128x128 bf16 in LDS [128][132], coalesced out
    unsigned short* lo16 = (unsigned short*)sm;
#pragma unroll
    for (int hb = 0; hb < 2; ++hb) {
        if (wm == hb) {
#pragma unroll
            for (int m = 0; m < 8; ++m)
#pragma unroll
              for (int qb = 0; qb < 2; ++qb) {
                f32x4 a = acc[m][qb];
#pragma unroll
                for (int j = 0; j < 4; ++j) {
                    float x = a[j];
                    if (MODE == 0) x = gelu_tanh(x);
                    lo16[(m * 16 + g * 4 + j) * 132 + wn * 32 + qb * 16 + rr] = f2bf(x);
                }
              }
        }
        __syncthreads();
#pragma unroll
        for (int rd = 0; rd < 4; ++rd) {
            const int idx = rd * 512 + tid;
            const int row = idx >> 4, c8 = (idx & 15) << 3;
            if (MODE == 0) {
                int4 v = *(const int4*)(lo16 + row * 132 + c8);
                *(int4*)(H + (size_t)(slot0 + hb * 128 + row) * FF + (size_t)tn * 128 + c8) = v;
            } else {
                const int tok = slot_token[slot0 + hb * 128 + row];
                if (tok >= 0) {
                    const float mp = maxprob[tok];
                    int4 yv = *(const int4*)(lo16 + row * 132 + c8);
                    const unsigned short* yy = (const unsigned short*)&yv;
                    const size_t go = (size_t)tok * DD + (size_t)tn * 128 + c8;
                    float4 d0 = *(const float4*)(data + go);
                    float4 d1 = *(const float4*)(data + go + 4);
                    float4 o0, o1;
                    o0.x = d0.x + mp * bf2f(yy[0]); o0.y = d0.y + mp * bf2f(yy[1]);
                    o0.z = d0.z + mp * bf2f(yy[2]); o0.w = d0.w + mp * bf2f(yy[3]);
                    o1.x = d1.x + mp * bf2f(yy[4]); o1.y = d1.y + mp * bf2f(yy[5]);
                    o1.z = d1.z + mp * bf2f(yy[6]); o1.w = d1.w + mp * bf2f(yy[7]);
                    *(float4*)(outF + go) = o0;
                    *(float4*)(outF + go + 4) = o1;
                }
            }
        }
        __syncthreads();
    }
}

// ---------- launch ----------
extern "C" void kernel_launch(void* const* d_in, const int* in_sizes, int n_in,
                              void* d_out, int out_size, void* d_ws, size_t ws_size,
                              hipStream_t stream)
{
    (void)in_sizes; (void)n_in; (void)out_size; (void)ws_size;
    const float* data   = (const float*)d_in[0];
    const float* gate_w = (const float*)d_in[1];
    const float* w1     = (const float*)d_in[2];
    const float* w2     = (const float*)d_in[3];
    const float* rms_w  = (const float*)d_in[4];

    float* outF   = (float*)d_out;
    float* logits = outF + (size_t)NTOK * DD;
    float* idxf   = logits + (size_t)NTOK * EE;

    char* ws = (char*)d_ws;
    const size_t SZ_NORM = (size_t)NTOK * DD * 2;        // 32 MB
    const size_t SZ_W1T  = (size_t)EE * DD * FF * 2;     // 32 MB
    const size_t SZ_W2T  = SZ_W1T;                       // 32 MB
    const size_t SZ_H    = (size_t)NSLOT * FF * 2;       // 80 MB
    unsigned short* norm_bf = (unsigned short*)(ws);
    unsigned short* w1T     = (unsigned short*)(ws + SZ_NORM);
    unsigned short* w2T     = (unsigned short*)(ws + SZ_NORM + SZ_W1T);
    unsigned short* Hbuf    = (unsigned short*)(ws + SZ_NORM + SZ_W1T + SZ_W2T);
    char* small             = ws + SZ_NORM + SZ_W1T + SZ_W2T + SZ_H;
    int*   slot_token = (int*)(small);
    int*   eidx       = (int*)(small + NSLOT * 4);
    float* maxprob    = (float*)(small + NSLOT * 4 + NTOK * 4);
    int*   zp         = (int*)(small + NSLOT * 4 + NTOK * 4 + NTOK * 4);

    k_rms_gate<<<NTOK, 256, 0, stream>>>(data, gate_w, rms_w, norm_bf, logits, maxprob, eidx, outF);
    k_route<<<BB, 256, 0, stream>>>(eidx, idxf, slot_token, zp);
    k_transcvt3<<<8192, 256, 0, stream>>>(w1, w2, w1T, w2T);
    k_gemm4<0, 1024, 2048><<<1280, 512, 0, stream>>>(norm_bf, w1T, Hbuf, slot_token,
                                                     nullptr, nullptr, nullptr, (const unsigned short*)zp);
    k_gemm4<1, 2048, 1024><<<640, 512, 0, stream>>>(Hbuf, w2T, nullptr, slot_token,
                                                    maxprob, data, outF, nullptr);
}